// Round 5
// baseline (10011.673 us; speedup 1.0000x reference)
//
#include <hip/hip_runtime.h>
#include <hip/hip_bf16.h>
#include <math.h>

#define K 4
#define F 513
#define B 4000
#define NIT 5
#define FB (F*B)
#define KB (K*B)        // 16000
#define NBLK 1024       // == exact co-residency capacity at 128 VGPR (4 blk/CU x 256 CU)
#define NTHR 256
#define NGRP 16         // barrier sub-groups
#define GSZ (NBLK/NGRP) // 64
#define NBC 8           // v b-chunks
#define BCH (B/NBC)     // 500
#define NVU (F*NBC)     // 4104 v units
#define B2 (B/2)        // 2000
#define NDU (129*B2)    // 258000 demix/final units (129 f-chunks x 2000 b-pairs)

// ---------------- persistent scratch: static device globals ------------------
__device__ float2 g_Wh[F*16];
__device__ float2 g_V[64*F];
__device__ float2 g_scale[F*4];
__device__ float  g_r2p[129*KB];
__device__ float4 g_phiT[B];

// two-level grid barrier state (zero-init; returns to initial state each pass)
__device__ unsigned g_cnt[NGRP*32];   // one counter per 128B to avoid line contention
__device__ unsigned g_root = 0;
__device__ unsigned g_sense = 0;

__device__ __forceinline__ void gsync(){
  __syncthreads();
  if (threadIdx.x == 0){
    __threadfence();
    unsigned s = __hip_atomic_load(&g_sense, __ATOMIC_RELAXED, __HIP_MEMORY_SCOPE_AGENT);
    unsigned grp = blockIdx.x & (NGRP-1);
    unsigned a = __hip_atomic_fetch_add(&g_cnt[grp*32], 1u, __ATOMIC_ACQ_REL, __HIP_MEMORY_SCOPE_AGENT);
    if (a == GSZ-1u){
      __hip_atomic_store(&g_cnt[grp*32], 0u, __ATOMIC_RELAXED, __HIP_MEMORY_SCOPE_AGENT);
      unsigned r = __hip_atomic_fetch_add(&g_root, 1u, __ATOMIC_ACQ_REL, __HIP_MEMORY_SCOPE_AGENT);
      if (r == NGRP-1u){
        __hip_atomic_store(&g_root, 0u, __ATOMIC_RELAXED, __HIP_MEMORY_SCOPE_AGENT);
        __hip_atomic_store(&g_sense, s+1u, __ATOMIC_RELEASE, __HIP_MEMORY_SCOPE_AGENT);
      } else {
        while (__hip_atomic_load(&g_sense, __ATOMIC_ACQUIRE, __HIP_MEMORY_SCOPE_AGENT) == s)
          __builtin_amdgcn_s_sleep(2);
      }
    } else {
      while (__hip_atomic_load(&g_sense, __ATOMIC_ACQUIRE, __HIP_MEMORY_SCOPE_AGENT) == s)
        __builtin_amdgcn_s_sleep(2);
    }
    __threadfence();
  }
  __syncthreads();
}

// ---------------- complex double helpers (tiny per-f solves only) -----------
struct cd { double re, im; };
__device__ inline cd mkcd(double r, double i){ cd z; z.re=r; z.im=i; return z; }
__device__ inline cd cmul(cd a, cd b){ return mkcd(a.re*b.re - a.im*b.im, a.re*b.im + a.im*b.re); }
__device__ inline cd cadd(cd a, cd b){ return mkcd(a.re+b.re, a.im+b.im); }
__device__ inline cd csub(cd a, cd b){ return mkcd(a.re-b.re, a.im-b.im); }
__device__ inline cd conj_(cd a){ return mkcd(a.re, -a.im); }
__device__ inline cd cdiv(cd a, cd b){
  double d = b.re*b.re + b.im*b.im;
  return mkcd((a.re*b.re + a.im*b.im)/d, (a.im*b.re - a.re*b.im)/d);
}
__device__ inline cd pf2(float2 a){ return mkcd((double)a.x, (double)a.y); }

// x = inv(M)[:,kk] via cofactors; M stored fp32 (matches reference precision),
// solve in fp64 (promote on use). Branch-free, no pivoting.
__device__ inline void invcol4f(const float2 Mf[16], int kk, cd x[4]){
  int r0 = (kk==0)?1:0;
  int r1 = (kk<=1)?2:1;
  int r2 = (kk<=2)?3:2;
  cd cof[4];
  #pragma unroll
  for (int i=0;i<4;++i){
    int c0 = (i==0)?1:0;
    int c1 = (i<=1)?2:1;
    int c2 = (i<=2)?3:2;
    cd m = cadd(csub(cmul(pf2(Mf[r0*4+c0]), csub(cmul(pf2(Mf[r1*4+c1]),pf2(Mf[r2*4+c2])),
                                                 cmul(pf2(Mf[r1*4+c2]),pf2(Mf[r2*4+c1])))),
                     cmul(pf2(Mf[r0*4+c1]), csub(cmul(pf2(Mf[r1*4+c0]),pf2(Mf[r2*4+c2])),
                                                 cmul(pf2(Mf[r1*4+c2]),pf2(Mf[r2*4+c0]))))),
                cmul(pf2(Mf[r0*4+c2]), csub(cmul(pf2(Mf[r1*4+c0]),pf2(Mf[r2*4+c1])),
                                            cmul(pf2(Mf[r1*4+c1]),pf2(Mf[r2*4+c0])))));
    if ((kk+i)&1) m = mkcd(-m.re,-m.im);
    cof[i] = m;
  }
  cd det = mkcd(0.0,0.0);
  #pragma unroll
  for (int i=0;i<4;++i) det = cadd(det, cmul(pf2(Mf[kk*4+i]), cof[i]));
  cd idet = cdiv(mkcd(1.0,0.0), det);
  #pragma unroll
  for (int i=0;i<4;++i) x[i] = cmul(cof[i], idet);
}

// ---------------- the single persistent kernel ------------------------------
__global__ __launch_bounds__(NTHR, 4) void auxiva_kernel(
    const float* __restrict__ Xr, const float* __restrict__ Xi,
    __hip_bfloat162* __restrict__ out){
  const int tid  = threadIdx.x;
  const int gtid = blockIdx.x*NTHR + tid;
  __shared__ float part[4*64];
  __shared__ float red[64];

  for (int it=0; it<NIT; ++it){
    // ---------- Phase A: demix partial r2 (r2p[y,k,b]) ----------
    if (gtid < NDU){
      int y = gtid / B2;
      int b = 2*(gtid - y*B2);
      float acc0[K], acc1[K];
      #pragma unroll
      for (int s=0;s<K;++s){ acc0[s]=0.0f; acc1[s]=0.0f; }
      auto body = [&](int f){
        float2 xr[K], xi[K];
        #pragma unroll
        for (int c=0;c<K;++c){
          int idx = c*FB + f*B + b;
          xr[c] = *reinterpret_cast<const float2*>(Xr + idx);
          xi[c] = *reinterpret_cast<const float2*>(Xi + idx);
        }
        if (it == 0){
          #pragma unroll
          for (int s=0;s<K;++s){
            acc0[s] += xr[s].x*xr[s].x + xi[s].x*xi[s].x;
            acc1[s] += xr[s].y*xr[s].y + xi[s].y*xi[s].y;
          }
        } else {
          const float2* w = g_Wh + f*16;
          #pragma unroll
          for (int s=0;s<K;++s){
            float yr0=0.0f, yi0=0.0f, yr1=0.0f, yi1=0.0f;
            #pragma unroll
            for (int c=0;c<K;++c){
              float2 ww = w[s*4+c];
              yr0 += ww.x*xr[c].x - ww.y*xi[c].x;
              yi0 += ww.x*xi[c].x + ww.y*xr[c].x;
              yr1 += ww.x*xr[c].y - ww.y*xi[c].y;
              yi1 += ww.x*xi[c].y + ww.y*xr[c].y;
            }
            acc0[s] += yr0*yr0 + yi0*yi0;
            acc1[s] += yr1*yr1 + yi1*yi1;
          }
        }
      };
      if (y < 128){
        int f0 = y*4;
        #pragma unroll
        for (int ff=0; ff<4; ++ff) body(f0+ff);
      } else {
        body(512);
      }
      #pragma unroll
      for (int s=0;s<K;++s)
        *reinterpret_cast<float2*>(g_r2p + y*KB + s*B + b) = make_float2(acc0[s], acc1[s]);
    }
    gsync();

    // ---------- Phase B: phi + zero g_V ----------
    if (gtid < KB){
      float s = 0.0f;
      #pragma unroll 8
      for (int y=0; y<129; ++y) s += g_r2p[y*KB + gtid];
      int k = gtid / B, b = gtid - k*B;
      reinterpret_cast<float*>(g_phiT)[b*4 + k] = 0.5f / sqrtf(s);
    } else if (gtid >= 16384 && gtid < 16384 + 2*64*F){
      reinterpret_cast<float*>(g_V)[gtid - 16384] = 0.0f;
    }
    gsync();

    // ---------- Phase C: V accumulate (atomic into g_V) ----------
    for (int u = blockIdx.x; u < NVU; u += NBLK){
      const int f = u >> 3;       // NBC = 8
      const int y = u & 7;
      float acc[64];
      #pragma unroll
      for (int q=0;q<64;++q) acc[q]=0.0f;

      if (tid < BCH/2){           // 250 active
        int b = y*BCH + 2*tid;
        float4 ph0 = g_phiT[b];
        float4 ph1 = g_phiT[b+1];
        float pk0[K] = {ph0.x, ph0.y, ph0.z, ph0.w};
        float pk1[K] = {ph1.x, ph1.y, ph1.z, ph1.w};
        float2 xr[K], xi[K];
        #pragma unroll
        for (int c=0;c<K;++c){
          int idx = c*FB + f*B + b;
          xr[c] = *reinterpret_cast<const float2*>(Xr + idx);
          xi[c] = *reinterpret_cast<const float2*>(Xi + idx);
        }
        { // b even
          float p[16];
          #pragma unroll
          for (int i=0;i<4;++i) p[i] = xr[i].x*xr[i].x + xi[i].x*xi[i].x;
          int s = 4;
          #pragma unroll
          for (int i=0;i<4;++i){
            #pragma unroll
            for (int j=i+1;j<4;++j){
              p[s++] = xr[i].x*xr[j].x + xi[i].x*xi[j].x;
              p[s++] = xi[i].x*xr[j].x - xr[i].x*xi[j].x;
            }
          }
          #pragma unroll
          for (int k=0;k<K;++k){
            #pragma unroll
            for (int q=0;q<16;++q) acc[k*16+q] += pk0[k]*p[q];
          }
        }
        { // b odd
          float p[16];
          #pragma unroll
          for (int i=0;i<4;++i) p[i] = xr[i].y*xr[i].y + xi[i].y*xi[i].y;
          int s = 4;
          #pragma unroll
          for (int i=0;i<4;++i){
            #pragma unroll
            for (int j=i+1;j<4;++j){
              p[s++] = xr[i].y*xr[j].y + xi[i].y*xi[j].y;
              p[s++] = xi[i].y*xr[j].y - xr[i].y*xi[j].y;
            }
          }
          #pragma unroll
          for (int k=0;k<K;++k){
            #pragma unroll
            for (int q=0;q<16;++q) acc[k*16+q] += pk1[k]*p[q];
          }
        }
      }

      int lane = tid & 63, wave = tid >> 6;
      // multi-value butterfly: after 6 steps lane l holds sum of original acc[l]
      #pragma unroll
      for (int d=0; d<6; ++d){
        const int sh = 1<<d;
        const bool hi = (lane & sh) != 0;
        #pragma unroll
        for (int m=0; m<(32>>d); ++m){
          float keep = hi ? acc[2*m+1] : acc[2*m];
          float send = hi ? acc[2*m]   : acc[2*m+1];
          acc[m] = keep + __shfl_xor(send, sh);
        }
      }
      part[wave*64 + lane] = acc[0];
      __syncthreads();
      if (tid < 64){
        red[tid] = (part[tid] + part[64+tid] + part[128+tid] + part[192+tid]) * (1.0f/B);
      }
      __syncthreads();
      if (tid < 64){
        int k = tid >> 4, ij = tid & 15, i = ij >> 2, j = ij & 3;
        float re, im;
        if (i == j){ re = red[k*16 + i]; im = 0.0f; }
        else {
          int a = min(i,j), c2 = max(i,j);
          int pidx = (a==0) ? (c2-1) : ((a==1) ? (c2+1) : 5);
          re = red[k*16 + 4 + 2*pidx];
          im = red[k*16 + 5 + 2*pidx];
          if (i > j) im = -im;
        }
        float* dst = reinterpret_cast<float*>(g_V) + ((unsigned)tid*F + f)*2;
        atomicAdd(dst,   re);
        atomicAdd(dst+1, im);
      }
    }
    gsync();

    // ---------- Phase D: per-f IP update (fp32 state, fp64 solve) ----------
    if (gtid < F){
      const int f = gtid;
      float2 Wf[16];
      if (it == 0){
        #pragma unroll
        for (int q=0;q<16;++q) Wf[q] = make_float2((q>>2)==(q&3) ? 1.0f : 0.0f, 0.0f);
      } else {
        #pragma unroll
        for (int q=0;q<16;++q) Wf[q] = g_Wh[f*16+q];
      }
      #pragma unroll
      for (int k=0;k<4;++k){
        float2 Vk[16];
        #pragma unroll
        for (int q=0;q<16;++q) Vk[q] = g_V[(k*16+q)*F + f];
        // M = Wh * Vk in fp32 (reference does this in complex64)
        float2 Mf[16];
        #pragma unroll
        for (int i=0;i<4;++i)
          #pragma unroll
          for (int j=0;j<4;++j){
            float mr=0.0f, mi=0.0f;
            #pragma unroll
            for (int c=0;c<4;++c){
              float2 a = Wf[i*4+c], v = Vk[c*4+j];
              mr += a.x*v.x - a.y*v.y;
              mi += a.x*v.y + a.y*v.x;
            }
            Mf[i*4+j] = make_float2(mr, mi);
          }
        cd x[4];
        invcol4f(Mf, k, x);               // x = inv(M)[:,k], fp64 solve
        cd w[4];
        #pragma unroll
        for (int c=0;c<4;++c) w[c] = conj_(x[c]);
        double dre = 0.0;
        #pragma unroll
        for (int j=0;j<4;++j){
          cd tj = mkcd(0.0,0.0);
          #pragma unroll
          for (int c=0;c<4;++c) tj = cadd(tj, cmul(w[c], pf2(Vk[c*4+j])));
          dre += tj.re*w[j].re + tj.im*w[j].im;
        }
        double inv_denom = rsqrt(dre > 0.0 ? dre : 1e-300);
        #pragma unroll
        for (int c=0;c<4;++c)
          Wf[k*4+c] = make_float2((float)(w[c].re*inv_denom), (float)(w[c].im*inv_denom));
      }
      #pragma unroll
      for (int q=0;q<16;++q) g_Wh[f*16+q] = Wf[q];
      if (it == NIT-1){
        cd x[4];
        invcol4f(Wf, 0, x);               // inv(Wh)[:,0]
        #pragma unroll
        for (int s=0;s<4;++s) g_scale[f*4+s] = make_float2((float)x[s].re, (float)x[s].im);
      }
    }
    gsync();
  }

  // ---------- Final: out = (Wh X) * scale, bf16 interleaved ----------
  if (gtid < NDU){
    int y = gtid / B2;
    int b = 2*(gtid - y*B2);
    auto body = [&](int f){
      float2 xr[K], xi[K];
      #pragma unroll
      for (int c=0;c<K;++c){
        int idx = c*FB + f*B + b;
        xr[c] = *reinterpret_cast<const float2*>(Xr + idx);
        xi[c] = *reinterpret_cast<const float2*>(Xi + idx);
      }
      const float2* w = g_Wh + f*16;
      #pragma unroll
      for (int s=0;s<K;++s){
        float yr0=0.0f, yi0=0.0f, yr1=0.0f, yi1=0.0f;
        #pragma unroll
        for (int c=0;c<K;++c){
          float2 ww = w[s*4+c];
          yr0 += ww.x*xr[c].x - ww.y*xi[c].x;
          yi0 += ww.x*xi[c].x + ww.y*xr[c].x;
          yr1 += ww.x*xr[c].y - ww.y*xi[c].y;
          yi1 += ww.x*xi[c].y + ww.y*xr[c].y;
        }
        float2 sc = g_scale[f*4+s];
        union { __hip_bfloat162 h2[2]; uint2 u; } uu;
        uu.h2[0].x = __float2bfloat16(yr0*sc.x - yi0*sc.y);
        uu.h2[0].y = __float2bfloat16(yr0*sc.y + yi0*sc.x);
        uu.h2[1].x = __float2bfloat16(yr1*sc.x - yi1*sc.y);
        uu.h2[1].y = __float2bfloat16(yr1*sc.y + yi1*sc.x);
        *reinterpret_cast<uint2*>(out + s*FB + f*B + b) = uu.u;
      }
    };
    if (y < 128){
      int f0 = y*4;
      #pragma unroll
      for (int ff=0; ff<4; ++ff) body(f0+ff);
    } else {
      body(512);
    }
  }
}

// ---------------- launch ----------------------------------------------------
extern "C" void kernel_launch(void* const* d_in, const int* in_sizes, int n_in,
                              void* d_out, int out_size, void* d_ws, size_t ws_size,
                              hipStream_t stream){
  // Inputs arrive alphabetized: d_in[0]="Xi", d_in[1]="Xr".
  const float* Xr = (const float*)d_in[1];
  const float* Xi = (const float*)d_in[0];
  __hip_bfloat162* out = (__hip_bfloat162*)d_out;
  auxiva_kernel<<<NBLK, NTHR, 0, stream>>>(Xr, Xi, out);
}

// Round 6
// 381.996 us; speedup vs baseline: 26.2088x; 26.2088x over previous
//
#include <hip/hip_runtime.h>
#include <hip/hip_bf16.h>
#include <math.h>

#define K 4
#define F 513
#define B 4000
#define NIT 5
#define FB (F*B)
#define KB (K*B)        // 16000
#define DFC 4           // f-chunk for demix/final (grid y=129; y<128 exact 4, y=128 -> f=512)
#define NDF 129
#define NBC 8           // b-chunks for v_kernel (4000/8=500)
#define BCH (B/NBC)     // 500

// ---------------- persistent scratch: static device globals ------------------
__device__ float2 g_Wh[F*16];     // (F,4,4) complex fp32 (written by update only)
__device__ float  g_Vk[64*F];     // packed-real V: (k*16+q, f); zeroed in phi, atomicAdd in v
__device__ float2 g_scale[F*4];   // (F,4) complex fp32
__device__ float  g_r2p[NDF*KB];  // per-f-chunk r2 partials
__device__ float  g_phi[KB];      // phi[k*B+b] (k-major: v_kernel wave k loads float2)

// ---------------- complex double helpers (tiny per-f solves only) -----------
struct cd { double re, im; };
__device__ inline cd mkcd(double r, double i){ cd z; z.re=r; z.im=i; return z; }
__device__ inline cd cmul(cd a, cd b){ return mkcd(a.re*b.re - a.im*b.im, a.re*b.im + a.im*b.re); }
__device__ inline cd cadd(cd a, cd b){ return mkcd(a.re+b.re, a.im+b.im); }
__device__ inline cd csub(cd a, cd b){ return mkcd(a.re-b.re, a.im-b.im); }
__device__ inline cd conj_(cd a){ return mkcd(a.re, -a.im); }
__device__ inline cd cdiv(cd a, cd b){
  double d = b.re*b.re + b.im*b.im;
  return mkcd((a.re*b.re + a.im*b.im)/d, (a.im*b.re - a.re*b.im)/d);
}

// x = inv(M)[:,kk] via cofactors (branch-free, no pivoting), full fp64.
__device__ inline void invcol4(const cd M[4][4], int kk, cd x[4]){
  int r0 = (kk==0)?1:0;
  int r1 = (kk<=1)?2:1;
  int r2 = (kk<=2)?3:2;
  cd cof[4];
  #pragma unroll
  for (int i=0;i<4;++i){
    int c0 = (i==0)?1:0;
    int c1 = (i<=1)?2:1;
    int c2 = (i<=2)?3:2;
    cd m = cadd(csub(cmul(M[r0][c0], csub(cmul(M[r1][c1],M[r2][c2]), cmul(M[r1][c2],M[r2][c1]))),
                     cmul(M[r0][c1], csub(cmul(M[r1][c0],M[r2][c2]), cmul(M[r1][c2],M[r2][c0])))),
                cmul(M[r0][c2], csub(cmul(M[r1][c0],M[r2][c1]), cmul(M[r1][c1],M[r2][c0]))));
    if ((kk+i)&1) m = mkcd(-m.re,-m.im);
    cof[i] = m;
  }
  cd det = mkcd(0.0,0.0);
  #pragma unroll
  for (int i=0;i<4;++i) det = cadd(det, cmul(M[kk][i], cof[i]));
  cd idet = cdiv(mkcd(1.0,0.0), det);
  #pragma unroll
  for (int i=0;i<4;++i) x[i] = cmul(cof[i], idet);
}

// ---------------- kernels ---------------------------------------------------

// partial r2: r2p[y,k,b] = sum over f-chunk y of |(Wh[f] X[:,f,b])[k]|^2
// it0: Wh = I -> Y = X (no init kernel needed).
__global__ __launch_bounds__(256) void demix_part_kernel(
    const float* __restrict__ Xr, const float* __restrict__ Xi, int it0){
  int t = blockIdx.x*blockDim.x + threadIdx.x;
  if (t >= B/2) return;
  int b = 2*t;
  int y = blockIdx.y;
  float acc0[K], acc1[K];
  #pragma unroll
  for (int s=0;s<K;++s){ acc0[s]=0.0f; acc1[s]=0.0f; }

  auto body = [&](int f){
    float2 xr[K], xi[K];
    #pragma unroll
    for (int c=0;c<K;++c){
      int idx = c*FB + f*B + b;
      xr[c] = *reinterpret_cast<const float2*>(Xr + idx);
      xi[c] = *reinterpret_cast<const float2*>(Xi + idx);
    }
    if (it0){
      #pragma unroll
      for (int s=0;s<K;++s){
        acc0[s] += xr[s].x*xr[s].x + xi[s].x*xi[s].x;
        acc1[s] += xr[s].y*xr[s].y + xi[s].y*xi[s].y;
      }
    } else {
      const float2* w = g_Wh + f*16;   // f uniform per block -> scalar loads
      #pragma unroll
      for (int s=0;s<K;++s){
        float yr0=0.0f, yi0=0.0f, yr1=0.0f, yi1=0.0f;
        #pragma unroll
        for (int c=0;c<K;++c){
          float2 ww = w[s*4+c];
          yr0 += ww.x*xr[c].x - ww.y*xi[c].x;
          yi0 += ww.x*xi[c].x + ww.y*xr[c].x;
          yr1 += ww.x*xr[c].y - ww.y*xi[c].y;
          yi1 += ww.x*xi[c].y + ww.y*xr[c].y;
        }
        acc0[s] += yr0*yr0 + yi0*yi0;
        acc1[s] += yr1*yr1 + yi1*yi1;
      }
    }
  };

  if (y < 128){
    int f0 = y*DFC;
    #pragma unroll
    for (int ff=0; ff<DFC; ++ff) body(f0+ff);
  } else {
    body(512);
  }
  #pragma unroll
  for (int s=0;s<K;++s)
    *reinterpret_cast<float2*>(g_r2p + y*KB + s*B + b) = make_float2(acc0[s], acc1[s]);
}

// phi[k*B+b] = 0.5 / sqrt( sum_y r2p[y,k,b] ); also zeroes g_Vk for v_kernel's
// atomic accumulation (129 blocks x 256 = 33024 threads cover 64*F=32832).
__global__ __launch_bounds__(256) void phi_kernel(){
  int t = blockIdx.x*blockDim.x + threadIdx.x;
  if (t < 64*F) g_Vk[t] = 0.0f;
  if (t >= KB) return;
  float s = 0.0f;
  #pragma unroll 8
  for (int y=0; y<NDF; ++y) s += g_r2p[y*KB + t];
  g_phi[t] = 0.5f / sqrtf(s);
}

// V accumulate, wave-per-k: wave k of each block computes acc[16] (packed
// quadratic terms weighted by phi[k]) over its b-chunk. acc footprint 64->16
// floats/thread => lb(256,6): 6 blocks/CU (was 4), grid (513,8)=16/CU avail.
// No LDS, no __syncthreads; in-wave butterfly + packed-real atomicAdd.
__global__ __launch_bounds__(256, 6) void v_kernel(
    const float* __restrict__ Xr, const float* __restrict__ Xi){
  const int f = blockIdx.x;
  const int y = blockIdx.y;
  const int tid = threadIdx.x;
  const int k = tid >> 6;          // wave id = source index k
  const int lane = tid & 63;

  float acc[16];
  #pragma unroll
  for (int q=0;q<16;++q) acc[q]=0.0f;

  const int b0 = y*BCH;
  #pragma unroll
  for (int i=0;i<4;++i){           // 250 b-pairs over 64 lanes -> 4 strided iters
    int pidx = lane + 64*i;
    if (pidx < BCH/2){
      int b = b0 + 2*pidx;
      float2 ph = *reinterpret_cast<const float2*>(g_phi + k*B + b);
      float2 xr[K], xi[K];
      #pragma unroll
      for (int c=0;c<K;++c){
        int idx = c*FB + f*B + b;
        xr[c] = *reinterpret_cast<const float2*>(Xr + idx);
        xi[c] = *reinterpret_cast<const float2*>(Xi + idx);
      }
      { // b even (.x)
        float p[16];
        #pragma unroll
        for (int a=0;a<4;++a) p[a] = xr[a].x*xr[a].x + xi[a].x*xi[a].x;
        int s = 4;
        #pragma unroll
        for (int a=0;a<4;++a){
          #pragma unroll
          for (int j=a+1;j<4;++j){
            p[s++] = xr[a].x*xr[j].x + xi[a].x*xi[j].x;
            p[s++] = xi[a].x*xr[j].x - xr[a].x*xi[j].x;
          }
        }
        #pragma unroll
        for (int q=0;q<16;++q) acc[q] += ph.x*p[q];
      }
      { // b odd (.y)
        float p[16];
        #pragma unroll
        for (int a=0;a<4;++a) p[a] = xr[a].y*xr[a].y + xi[a].y*xi[a].y;
        int s = 4;
        #pragma unroll
        for (int a=0;a<4;++a){
          #pragma unroll
          for (int j=a+1;j<4;++j){
            p[s++] = xr[a].y*xr[j].y + xi[a].y*xi[j].y;
            p[s++] = xi[a].y*xr[j].y - xr[a].y*xi[j].y;
          }
        }
        #pragma unroll
        for (int q=0;q<16;++q) acc[q] += ph.y*p[q];
      }
    }
  }

  // multi-value butterfly: after 4 steps slot 0 holds value (lane&15) summed
  // over each 16-lane group; 2 xor steps combine the 4 groups.
  #pragma unroll
  for (int d=0; d<4; ++d){
    const int sh = 1<<d;
    const bool hi = (lane & sh) != 0;
    #pragma unroll
    for (int m=0; m<(8>>d); ++m){
      float keep = hi ? acc[2*m+1] : acc[2*m];   // static indices: no scratch
      float send = hi ? acc[2*m]   : acc[2*m+1];
      acc[m] = keep + __shfl_xor(send, sh);
    }
  }
  acc[0] += __shfl_xor(acc[0], 16);
  acc[0] += __shfl_xor(acc[0], 32);

  if (lane < 16)
    atomicAdd(&g_Vk[(k*16 + lane)*F + f], acc[0] * (1.0f/B));
}

// Per-f IP updates k=0..3 (sequential), fp64 cofactor solves, branch-free.
// 64 packed V values prefetched in one coalesced batch (latency paid once).
__global__ __launch_bounds__(64, 1) void update_kernel(int it0, int do_scale){
  int f = blockIdx.x*blockDim.x + threadIdx.x;
  if (f >= F) return;

  float Vf[64];
  #pragma unroll
  for (int q=0;q<64;++q) Vf[q] = g_Vk[q*F + f];

  cd W[4][4];
  if (it0){
    #pragma unroll
    for (int s=0;s<4;++s)
      #pragma unroll
      for (int c=0;c<4;++c) W[s][c] = mkcd(s==c ? 1.0 : 0.0, 0.0);
  } else {
    #pragma unroll
    for (int s=0;s<4;++s)
      #pragma unroll
      for (int c=0;c<4;++c){ float2 w = g_Wh[f*16+s*4+c]; W[s][c] = mkcd((double)w.x,(double)w.y); }
  }

  #pragma unroll
  for (int k=0;k<4;++k){
    const float* vk = Vf + k*16;
    // expand packed 16 reals -> hermitian 4x4 complex
    cd Vk[4][4];
    #pragma unroll
    for (int i=0;i<4;++i)
      #pragma unroll
      for (int j=0;j<4;++j){
        if (i == j) Vk[i][j] = mkcd((double)vk[i], 0.0);
        else {
          int a = min(i,j), c2 = max(i,j);
          int pidx = (a==0) ? (c2-1) : ((a==1) ? (c2+1) : 5);
          double re = (double)vk[4 + 2*pidx];
          double im = (double)vk[5 + 2*pidx];
          Vk[i][j] = mkcd(re, (i > j) ? -im : im);
        }
      }
    cd M[4][4];
    #pragma unroll
    for (int i=0;i<4;++i)
      #pragma unroll
      for (int j=0;j<4;++j){
        cd s = mkcd(0.0,0.0);
        #pragma unroll
        for (int c=0;c<4;++c) s = cadd(s, cmul(W[i][c], Vk[c][j]));
        M[i][j] = s;
      }
    cd x[4];
    invcol4(M, k, x);                  // x = inv(M)[:,k]
    cd w[4];
    #pragma unroll
    for (int c=0;c<4;++c) w[c] = conj_(x[c]);
    double dre = 0.0;
    #pragma unroll
    for (int j=0;j<4;++j){
      cd tj = mkcd(0.0,0.0);
      #pragma unroll
      for (int c=0;c<4;++c) tj = cadd(tj, cmul(w[c], Vk[c][j]));
      dre += tj.re*w[j].re + tj.im*w[j].im;   // Re(tj * conj(w_j))
    }
    double inv_denom = rsqrt(dre > 0.0 ? dre : 1e-300);
    #pragma unroll
    for (int c=0;c<4;++c) W[k][c] = mkcd(w[c].re*inv_denom, w[c].im*inv_denom);
  }
  #pragma unroll
  for (int s=0;s<4;++s)
    #pragma unroll
    for (int c=0;c<4;++c) g_Wh[f*16+s*4+c] = make_float2((float)W[s][c].re, (float)W[s][c].im);

  if (do_scale){
    cd x[4];
    invcol4(W, 0, x);   // x = inv(Wh)[:,0]
    #pragma unroll
    for (int s=0;s<4;++s) g_scale[f*4+s] = make_float2((float)x[s].re, (float)x[s].im);
  }
}

// out[s,f,b] = (Wh[f] X[:,f,b])[s] * scale[f,s]; 2 b per thread, 8B packed stores
__global__ __launch_bounds__(256) void final_kernel(
    const float* __restrict__ Xr, const float* __restrict__ Xi,
    __hip_bfloat162* __restrict__ out){
  int t = blockIdx.x*blockDim.x + threadIdx.x;
  if (t >= B/2) return;
  int b = 2*t;
  int y = blockIdx.y;

  auto body = [&](int f){
    float2 xr[K], xi[K];
    #pragma unroll
    for (int c=0;c<K;++c){
      int idx = c*FB + f*B + b;
      xr[c] = *reinterpret_cast<const float2*>(Xr + idx);
      xi[c] = *reinterpret_cast<const float2*>(Xi + idx);
    }
    const float2* w = g_Wh + f*16;
    #pragma unroll
    for (int s=0;s<K;++s){
      float yr0=0.0f, yi0=0.0f, yr1=0.0f, yi1=0.0f;
      #pragma unroll
      for (int c=0;c<K;++c){
        float2 ww = w[s*4+c];
        yr0 += ww.x*xr[c].x - ww.y*xi[c].x;
        yi0 += ww.x*xi[c].x + ww.y*xr[c].x;
        yr1 += ww.x*xr[c].y - ww.y*xi[c].y;
        yi1 += ww.x*xi[c].y + ww.y*xr[c].y;
      }
      float2 sc = g_scale[f*4+s];
      union { __hip_bfloat162 h2[2]; uint2 u; } uu;
      uu.h2[0].x = __float2bfloat16(yr0*sc.x - yi0*sc.y);
      uu.h2[0].y = __float2bfloat16(yr0*sc.y + yi0*sc.x);
      uu.h2[1].x = __float2bfloat16(yr1*sc.x - yi1*sc.y);
      uu.h2[1].y = __float2bfloat16(yr1*sc.y + yi1*sc.x);
      *reinterpret_cast<uint2*>(out + s*FB + f*B + b) = uu.u;
    }
  };

  if (y < 128){
    int f0 = y*DFC;
    #pragma unroll
    for (int ff=0; ff<DFC; ++ff) body(f0+ff);
  } else {
    body(512);
  }
}

// ---------------- launch ----------------------------------------------------
extern "C" void kernel_launch(void* const* d_in, const int* in_sizes, int n_in,
                              void* d_out, int out_size, void* d_ws, size_t ws_size,
                              hipStream_t stream){
  // Inputs arrive alphabetized: d_in[0]="Xi", d_in[1]="Xr".
  const float* Xr = (const float*)d_in[1];
  const float* Xi = (const float*)d_in[0];
  __hip_bfloat162* out = (__hip_bfloat162*)d_out;

  dim3 gD((B/2 + 255)/256, NDF);        // (8, 129)
  dim3 gV(F, NBC);                      // (513, 8)
  for (int it=0; it<NIT; ++it){
    demix_part_kernel<<<gD, 256, 0, stream>>>(Xr, Xi, it == 0 ? 1 : 0);
    phi_kernel<<<NDF, 256, 0, stream>>>();
    v_kernel<<<gV, 256, 0, stream>>>(Xr, Xi);
    update_kernel<<<(F + 63)/64, 64, 0, stream>>>(it == 0 ? 1 : 0, it == NIT-1 ? 1 : 0);
  }
  final_kernel<<<gD, 256, 0, stream>>>(Xr, Xi, out);
}

// Round 7
// 354.123 us; speedup vs baseline: 28.2717x; 1.0787x over previous
//
#include <hip/hip_runtime.h>
#include <hip/hip_bf16.h>
#include <math.h>

#define K 4
#define F 513
#define B 4000
#define NIT 5
#define FB (F*B)
#define KB (K*B)
#define FCH 8         // f-chunk for demix/final
#define NFC 65        // ceil(513/8)
#define NBC 4         // b-chunks for v_kernel (B divisible: 4000/4=1000)
#define BCH (B/NBC)

// ---------------- persistent scratch: static device globals ------------------
__device__ float2 g_Wh[F*16];        // (F,4,4) complex fp32
__device__ float2 g_Vp[NBC*64*F];    // per-b-chunk partial V: (y, k*16+q, f)
__device__ float2 g_scale[F*4];      // (F,4) complex fp32
__device__ float  g_r2p[NFC*KB];     // per-chunk partials (plain stores, no init needed)
__device__ float  g_phi[KB];         // phi[k,b] = 0.5/sqrt(r2) precomputed once per iter

// ---------------- complex double helpers (tiny per-f solves only) -----------
struct cd { double re, im; };
__device__ inline cd mkcd(double r, double i){ cd z; z.re=r; z.im=i; return z; }
__device__ inline cd cmul(cd a, cd b){ return mkcd(a.re*b.re - a.im*b.im, a.re*b.im + a.im*b.re); }
__device__ inline cd cadd(cd a, cd b){ return mkcd(a.re+b.re, a.im+b.im); }
__device__ inline cd csub(cd a, cd b){ return mkcd(a.re-b.re, a.im-b.im); }
__device__ inline cd conj_(cd a){ return mkcd(a.re, -a.im); }
__device__ inline cd cdiv(cd a, cd b){
  double d = b.re*b.re + b.im*b.im;
  return mkcd((a.re*b.re + a.im*b.im)/d, (a.im*b.re - a.re*b.im)/d);
}

// x = inv(M)[:,kk] via cofactors (branch-free, no pivoting).
__device__ inline void invcol4(const cd M[4][4], int kk, cd x[4]){
  int r0 = (kk==0)?1:0;
  int r1 = (kk<=1)?2:1;
  int r2 = (kk<=2)?3:2;
  cd cof[4];
  #pragma unroll
  for (int i=0;i<4;++i){
    int c0 = (i==0)?1:0;
    int c1 = (i<=1)?2:1;
    int c2 = (i<=2)?3:2;
    cd m = cadd(csub(cmul(M[r0][c0], csub(cmul(M[r1][c1],M[r2][c2]), cmul(M[r1][c2],M[r2][c1]))),
                     cmul(M[r0][c1], csub(cmul(M[r1][c0],M[r2][c2]), cmul(M[r1][c2],M[r2][c0])))),
                cmul(M[r0][c2], csub(cmul(M[r1][c0],M[r2][c1]), cmul(M[r1][c1],M[r2][c0]))));
    if ((kk+i)&1) m = mkcd(-m.re,-m.im);
    cof[i] = m;
  }
  cd det = mkcd(0.0,0.0);
  #pragma unroll
  for (int i=0;i<4;++i) det = cadd(det, cmul(M[kk][i], cof[i]));
  cd idet = cdiv(mkcd(1.0,0.0), det);
  #pragma unroll
  for (int i=0;i<4;++i) x[i] = cmul(cof[i], idet);
}

// ---------------- kernels ---------------------------------------------------

__global__ void init_kernel(){
  int t = blockIdx.x*blockDim.x + threadIdx.x;
  if (t < F*16){
    int sc = t & 15; int s = sc >> 2, c = sc & 3;
    g_Wh[t] = make_float2(s==c ? 1.0f : 0.0f, 0.0f);
  }
}

// partial r2: r2p[y,k,b] = sum over f-chunk y of |(Wh[f] X[:,f,b])[k]|^2
__global__ __launch_bounds__(256) void demix_part_kernel(
    const float* __restrict__ Xr, const float* __restrict__ Xi){
  int b = blockIdx.x*blockDim.x + threadIdx.x;
  if (b >= B) return;
  int y = blockIdx.y;
  int f0 = y*FCH, f1 = min(f0+FCH, F);
  float acc[K];
  #pragma unroll
  for (int s=0;s<K;++s) acc[s]=0.0f;
  for (int f=f0; f<f1; ++f){
    float xr[K], xi[K];
    #pragma unroll
    for (int c=0;c<K;++c){ int idx=c*FB + f*B + b; xr[c]=Xr[idx]; xi[c]=Xi[idx]; }
    const float2* w = g_Wh + f*16;
    #pragma unroll
    for (int s=0;s<K;++s){
      float yr=0.0f, yi=0.0f;
      #pragma unroll
      for (int c=0;c<K;++c){
        float2 ww = w[s*4+c];
        yr += ww.x*xr[c] - ww.y*xi[c];
        yi += ww.x*xi[c] + ww.y*xr[c];
      }
      acc[s] += yr*yr + yi*yi;
    }
  }
  #pragma unroll
  for (int s=0;s<K;++s) g_r2p[y*KB + s*B + b] = acc[s];
}

// phi[k,b] = 0.5 / sqrt( sum_y r2p[y,k,b] )
__global__ __launch_bounds__(256) void phi_kernel(){
  int t = blockIdx.x*blockDim.x + threadIdx.x;
  if (t >= KB) return;
  float s = 0.0f;
  #pragma unroll 5
  for (int y=0; y<NFC; ++y) s += g_r2p[y*KB + t];
  g_phi[t] = 0.5f / sqrtf(s);
}

// Partial V over a b-chunk: Vp[y,k,ij,f] = (1/B) sum_{b in chunk y} phi[k,b] p[ij](f,b)
// Grid (F, NBC) -> 2052 blocks.
__global__ __launch_bounds__(256, 4) void v_kernel(
    const float* __restrict__ Xr, const float* __restrict__ Xi){
  int f = blockIdx.x;
  int y = blockIdx.y;
  int tid = threadIdx.x;
  float acc[64];
  #pragma unroll
  for (int q=0;q<64;++q) acc[q]=0.0f;

  int b0 = y*BCH;
  for (int b = b0 + tid; b < b0 + BCH; b += 256){
    float phi[K];
    #pragma unroll
    for (int k=0;k<K;++k) phi[k] = g_phi[k*B+b];
    float xr[K], xi[K];
    #pragma unroll
    for (int c=0;c<K;++c){ int idx=c*FB + f*B + b; xr[c]=Xr[idx]; xi[c]=Xi[idx]; }
    float p[16];
    #pragma unroll
    for (int i=0;i<4;++i) p[i] = xr[i]*xr[i] + xi[i]*xi[i];
    int s = 4;
    #pragma unroll
    for (int i=0;i<4;++i){
      #pragma unroll
      for (int j=i+1;j<4;++j){
        p[s++] = xr[i]*xr[j] + xi[i]*xi[j];
        p[s++] = xi[i]*xr[j] - xr[i]*xi[j];
      }
    }
    #pragma unroll
    for (int k=0;k<K;++k){
      #pragma unroll
      for (int q=0;q<16;++q) acc[k*16+q] += phi[k]*p[q];
    }
  }

  int lane = tid & 63, wave = tid >> 6;
  // Multi-value butterfly: 63 shfl_xor; after 6 steps lane l holds (in acc[0])
  // the wave-wide sum of original acc[l].
  #pragma unroll
  for (int d=0; d<6; ++d){
    const int sh = 1<<d;
    const bool hi = (lane & sh) != 0;
    #pragma unroll
    for (int m=0; m<(32>>d); ++m){
      float keep = hi ? acc[2*m+1] : acc[2*m];   // static indices: no scratch
      float send = hi ? acc[2*m]   : acc[2*m+1];
      acc[m] = keep + __shfl_xor(send, sh);
    }
  }

  __shared__ float part[4*64];
  __shared__ float red[64];
  part[wave*64 + lane] = acc[0];
  __syncthreads();
  if (tid < 64){
    red[tid] = (part[tid] + part[64+tid] + part[128+tid] + part[192+tid]) * (1.0f/B);
  }
  __syncthreads();
  if (tid < 64){
    int k = tid >> 4, ij = tid & 15, i = ij >> 2, j = ij & 3;
    float re, im;
    if (i == j){ re = red[k*16 + i]; im = 0.0f; }
    else {
      int a = min(i,j), c2 = max(i,j);
      int pidx = (a==0) ? (c2-1) : ((a==1) ? (c2+1) : 5);
      re = red[k*16 + 4 + 2*pidx];
      im = red[k*16 + 5 + 2*pidx];
      if (i > j) im = -im;
    }
    g_Vp[(unsigned)tid*F*NBC/NBC*0 + (y*64 + (unsigned)tid)*F + f] = make_float2(re, im);
  }
}

// Per-f IP updates k=0..3 (sequential), fp64 cofactor solves, branch-free.
// ONLY change vs the 356 µs baseline: per-k batched prefetch of the 64
// independent g_Vp float2 loads (static indices -> registers, no scratch),
// collapsing 64 dependent load->add latency waits into ~4. Sum order over y
// is unchanged (ascending) -> bit-identical numerics.
__global__ __launch_bounds__(64, 1) void update_kernel(int do_scale){
  int f = blockIdx.x*blockDim.x + threadIdx.x;
  if (f >= F) return;
  cd W[4][4];
  #pragma unroll
  for (int s=0;s<4;++s)
    #pragma unroll
    for (int c=0;c<4;++c){ float2 w = g_Wh[f*16+s*4+c]; W[s][c] = mkcd((double)w.x,(double)w.y); }

  #pragma unroll
  for (int k=0;k<4;++k){
    float2 vp[NBC][16];
    #pragma unroll
    for (int y=0;y<NBC;++y)
      #pragma unroll
      for (int q=0;q<16;++q)
        vp[y][q] = g_Vp[(y*64 + k*16 + q)*F + f];
    cd Vk[4][4];
    #pragma unroll
    for (int i=0;i<4;++i)
      #pragma unroll
      for (int j=0;j<4;++j){
        int q = i*4 + j;
        float2 vv = make_float2(0.0f, 0.0f);
        #pragma unroll
        for (int y=0;y<NBC;++y){ vv.x += vp[y][q].x; vv.y += vp[y][q].y; }
        Vk[i][j] = mkcd((double)vv.x,(double)vv.y);
      }
    cd M[4][4];
    #pragma unroll
    for (int i=0;i<4;++i)
      #pragma unroll
      for (int j=0;j<4;++j){
        cd s = mkcd(0.0,0.0);
        #pragma unroll
        for (int c=0;c<4;++c) s = cadd(s, cmul(W[i][c], Vk[c][j]));
        M[i][j] = s;
      }
    cd x[4];
    invcol4(M, k, x);                  // x = inv(M)[:,k]
    cd w[4];
    #pragma unroll
    for (int c=0;c<4;++c) w[c] = conj_(x[c]);
    double dre = 0.0;
    #pragma unroll
    for (int j=0;j<4;++j){
      cd tj = mkcd(0.0,0.0);
      #pragma unroll
      for (int c=0;c<4;++c) tj = cadd(tj, cmul(w[c], Vk[c][j]));
      dre += tj.re*w[j].re + tj.im*w[j].im;   // Re(tj * conj(w_j))
    }
    double inv_denom = rsqrt(dre > 0.0 ? dre : 1e-300);
    #pragma unroll
    for (int c=0;c<4;++c) W[k][c] = mkcd(w[c].re*inv_denom, w[c].im*inv_denom);
  }
  #pragma unroll
  for (int s=0;s<4;++s)
    #pragma unroll
    for (int c=0;c<4;++c) g_Wh[f*16+s*4+c] = make_float2((float)W[s][c].re, (float)W[s][c].im);

  if (do_scale){
    cd x[4];
    invcol4(W, 0, x);   // x = inv(Wh)[:,0]
    #pragma unroll
    for (int s=0;s<4;++s) g_scale[f*4+s] = make_float2((float)x[s].re, (float)x[s].im);
  }
}

// out[s,f,b] = (Wh[f] X[:,f,b])[s] * scale[f,s]; interleaved (re,im) bf16 pairs
__global__ __launch_bounds__(256) void final_kernel(
    const float* __restrict__ Xr, const float* __restrict__ Xi,
    __hip_bfloat162* __restrict__ out){
  int b = blockIdx.x*blockDim.x + threadIdx.x;
  if (b >= B) return;
  int f0 = blockIdx.y*FCH, f1 = min(f0+FCH, F);
  for (int f=f0; f<f1; ++f){
    float xr[K], xi[K];
    #pragma unroll
    for (int c=0;c<K;++c){ int idx=c*FB + f*B + b; xr[c]=Xr[idx]; xi[c]=Xi[idx]; }
    const float2* w = g_Wh + f*16;
    #pragma unroll
    for (int s=0;s<K;++s){
      float yr=0.0f, yi=0.0f;
      #pragma unroll
      for (int c=0;c<K;++c){
        float2 ww = w[s*4+c];
        yr += ww.x*xr[c] - ww.y*xi[c];
        yi += ww.x*xi[c] + ww.y*xr[c];
      }
      float2 sc = g_scale[f*4+s];
      __hip_bfloat162 o;
      o.x = __float2bfloat16(yr*sc.x - yi*sc.y);
      o.y = __float2bfloat16(yr*sc.y + yi*sc.x);
      out[s*FB + f*B + b] = o;
    }
  }
}

// ---------------- launch ----------------------------------------------------
extern "C" void kernel_launch(void* const* d_in, const int* in_sizes, int n_in,
                              void* d_out, int out_size, void* d_ws, size_t ws_size,
                              hipStream_t stream){
  // Inputs arrive alphabetized: d_in[0]="Xi", d_in[1]="Xr".
  const float* Xr = (const float*)d_in[1];
  const float* Xi = (const float*)d_in[0];
  __hip_bfloat162* out = (__hip_bfloat162*)d_out;

  init_kernel<<<33, 256, 0, stream>>>();
  dim3 gD((B + 255)/256, NFC);          // (16, 65)
  dim3 gV(F, NBC);                      // (513, 4)
  for (int it=0; it<NIT; ++it){
    demix_part_kernel<<<gD, 256, 0, stream>>>(Xr, Xi);
    phi_kernel<<<(KB + 255)/256, 256, 0, stream>>>();
    v_kernel<<<gV, 256, 0, stream>>>(Xr, Xi);
    update_kernel<<<(F + 63)/64, 64, 0, stream>>>(it == NIT-1 ? 1 : 0);
  }
  final_kernel<<<gD, 256, 0, stream>>>(Xr, Xi, out);
}

// Round 9
// 351.622 us; speedup vs baseline: 28.4728x; 1.0071x over previous
//
#include <hip/hip_runtime.h>
#include <hip/hip_bf16.h>
#include <math.h>

#define K 4
#define F 513
#define B 4000
#define NIT 5
#define FB (F*B)
#define KB (K*B)      // 16000
#define FCH 8         // f-chunk for demix/final
#define NFC 65        // ceil(513/8)
#define NBC 4         // b-chunks for v_kernel
#define BCH (B/NBC)   // 1000

// ---------------- persistent scratch: static device globals ------------------
__device__ float2 g_Wh[F*16];        // (F,4,4) complex fp32
__device__ float2 g_Vp[NBC*64*F];    // per-b-chunk partial V: (y, k*16+q, f)
__device__ float2 g_scale[F*4];      // (F,4) complex fp32
__device__ float  g_r2[2][KB];       // double-buffered r2 (atomicAdd from demix)

// ---------------- complex double helpers (tiny per-f solves only) -----------
struct cd { double re, im; };
__device__ inline cd mkcd(double r, double i){ cd z; z.re=r; z.im=i; return z; }
__device__ inline cd cmul(cd a, cd b){ return mkcd(a.re*b.re - a.im*b.im, a.re*b.im + a.im*b.re); }
__device__ inline cd cadd(cd a, cd b){ return mkcd(a.re+b.re, a.im+b.im); }
__device__ inline cd csub(cd a, cd b){ return mkcd(a.re-b.re, a.im-b.im); }
__device__ inline cd conj_(cd a){ return mkcd(a.re, -a.im); }
__device__ inline cd cdiv(cd a, cd b){
  double d = b.re*b.re + b.im*b.im;
  return mkcd((a.re*b.re + a.im*b.im)/d, (a.im*b.re - a.re*b.im)/d);
}

// x = inv(M)[:,kk] via cofactors (branch-free, no pivoting), full fp64.
__device__ inline void invcol4(const cd M[4][4], int kk, cd x[4]){
  int r0 = (kk==0)?1:0;
  int r1 = (kk<=1)?2:1;
  int r2 = (kk<=2)?3:2;
  cd cof[4];
  #pragma unroll
  for (int i=0;i<4;++i){
    int c0 = (i==0)?1:0;
    int c1 = (i<=1)?2:1;
    int c2 = (i<=2)?3:2;
    cd m = cadd(csub(cmul(M[r0][c0], csub(cmul(M[r1][c1],M[r2][c2]), cmul(M[r1][c2],M[r2][c1]))),
                     cmul(M[r0][c1], csub(cmul(M[r1][c0],M[r2][c2]), cmul(M[r1][c2],M[r2][c0])))),
                cmul(M[r0][c2], csub(cmul(M[r1][c0],M[r2][c1]), cmul(M[r1][c1],M[r2][c0]))));
    if ((kk+i)&1) m = mkcd(-m.re,-m.im);
    cof[i] = m;
  }
  cd det = mkcd(0.0,0.0);
  #pragma unroll
  for (int i=0;i<4;++i) det = cadd(det, cmul(M[kk][i], cof[i]));
  cd idet = cdiv(mkcd(1.0,0.0), det);
  #pragma unroll
  for (int i=0;i<4;++i) x[i] = cmul(cof[i], idet);
}

// ---------------- kernels ---------------------------------------------------

__global__ void init_kernel(){
  int t = blockIdx.x*blockDim.x + threadIdx.x;     // 33*256 = 8448 threads
  if (t < F*16){
    int sc = t & 15;
    g_Wh[t] = make_float2((sc>>2)==(sc&3) ? 1.0f : 0.0f, 0.0f);
  }
  for (int j=t; j<KB; j+=33*256) g_r2[0][j] = 0.0f;
}

// partial r2 accumulated straight into g_r2[pb] via atomicAdd (65 adders per
// address over the dispatch, 16000 distinct dwords -> negligible contention).
__global__ __launch_bounds__(256) void demix_part_kernel(
    const float* __restrict__ Xr, const float* __restrict__ Xi, int pb){
  int b = blockIdx.x*blockDim.x + threadIdx.x;
  if (b >= B) return;
  int y = blockIdx.y;
  int f0 = y*FCH, f1 = min(f0+FCH, F);
  float acc[K];
  #pragma unroll
  for (int s=0;s<K;++s) acc[s]=0.0f;
  for (int f=f0; f<f1; ++f){
    float xr[K], xi[K];
    #pragma unroll
    for (int c=0;c<K;++c){ int idx=c*FB + f*B + b; xr[c]=Xr[idx]; xi[c]=Xi[idx]; }
    const float2* w = g_Wh + f*16;
    #pragma unroll
    for (int s=0;s<K;++s){
      float yr=0.0f, yi=0.0f;
      #pragma unroll
      for (int c=0;c<K;++c){
        float2 ww = w[s*4+c];
        yr += ww.x*xr[c] - ww.y*xi[c];
        yi += ww.x*xi[c] + ww.y*xr[c];
      }
      acc[s] += yr*yr + yi*yi;
    }
  }
  #pragma unroll
  for (int s=0;s<K;++s) atomicAdd(&g_r2[pb][s*B + b], acc[s]);
}

// Partial V over a b-chunk: Vp[y,k,ij,f] = (1/B) sum_{b in chunk y} phi[k,b] p[ij](f,b)
// phi computed inline from g_r2[pb] (replaces the dedicated phi_kernel launch).
__global__ __launch_bounds__(256, 4) void v_kernel(
    const float* __restrict__ Xr, const float* __restrict__ Xi, int pb){
  int f = blockIdx.x;
  int y = blockIdx.y;
  int tid = threadIdx.x;
  float acc[64];
  #pragma unroll
  for (int q=0;q<64;++q) acc[q]=0.0f;

  int b0 = y*BCH;
  for (int b = b0 + tid; b < b0 + BCH; b += 256){
    float phi[K];
    #pragma unroll
    for (int k=0;k<K;++k) phi[k] = 0.5f / sqrtf(g_r2[pb][k*B+b]);
    float xr[K], xi[K];
    #pragma unroll
    for (int c=0;c<K;++c){ int idx=c*FB + f*B + b; xr[c]=Xr[idx]; xi[c]=Xi[idx]; }
    float p[16];
    #pragma unroll
    for (int i=0;i<4;++i) p[i] = xr[i]*xr[i] + xi[i]*xi[i];
    int s = 4;
    #pragma unroll
    for (int i=0;i<4;++i){
      #pragma unroll
      for (int j=i+1;j<4;++j){
        p[s++] = xr[i]*xr[j] + xi[i]*xi[j];
        p[s++] = xi[i]*xr[j] - xr[i]*xi[j];
      }
    }
    #pragma unroll
    for (int k=0;k<K;++k){
      #pragma unroll
      for (int q=0;q<16;++q) acc[k*16+q] += phi[k]*p[q];
    }
  }

  int lane = tid & 63, wave = tid >> 6;
  // Multi-value butterfly: 63 shfl_xor; after 6 steps lane l holds (in acc[0])
  // the wave-wide sum of original acc[l].
  #pragma unroll
  for (int d=0; d<6; ++d){
    const int sh = 1<<d;
    const bool hi = (lane & sh) != 0;
    #pragma unroll
    for (int m=0; m<(32>>d); ++m){
      float keep = hi ? acc[2*m+1] : acc[2*m];   // static indices: no scratch
      float send = hi ? acc[2*m]   : acc[2*m+1];
      acc[m] = keep + __shfl_xor(send, sh);
    }
  }

  __shared__ float part[4*64];
  __shared__ float red[64];
  part[wave*64 + lane] = acc[0];
  __syncthreads();
  if (tid < 64){
    red[tid] = (part[tid] + part[64+tid] + part[128+tid] + part[192+tid]) * (1.0f/B);
  }
  __syncthreads();
  if (tid < 64){
    int k = tid >> 4, ij = tid & 15, i = ij >> 2, j = ij & 3;
    float re, im;
    if (i == j){ re = red[k*16 + i]; im = 0.0f; }
    else {
      int a = min(i,j), c2 = max(i,j);
      int pidx = (a==0) ? (c2-1) : ((a==1) ? (c2+1) : 5);
      re = red[k*16 + 4 + 2*pidx];
      im = red[k*16 + 5 + 2*pidx];
      if (i > j) im = -im;
    }
    g_Vp[(y*64 + (unsigned)tid)*F + f] = make_float2(re, im);
  }
}

// Per-f IP updates k=0..3 (sequential), fp64 cofactor solves, branch-free.
// Per-k batched prefetch of the 64 independent g_Vp float2 loads (R7-proven).
// Also zeroes the other r2 buffer for the next iteration's demix atomics.
__global__ __launch_bounds__(64, 1) void update_kernel(int do_scale, int pb){
  int t = blockIdx.x*blockDim.x + threadIdx.x;
  // zero next r2 buffer (576 threads, coalesced, ~28 stores each)
  for (int j=t; j<KB; j+=576) g_r2[pb^1][j] = 0.0f;
  int f = t;
  if (f >= F) return;
  cd W[4][4];
  #pragma unroll
  for (int s=0;s<4;++s)
    #pragma unroll
    for (int c=0;c<4;++c){ float2 w = g_Wh[f*16+s*4+c]; W[s][c] = mkcd((double)w.x,(double)w.y); }

  #pragma unroll
  for (int k=0;k<4;++k){
    float2 vp[NBC][16];
    #pragma unroll
    for (int y=0;y<NBC;++y)
      #pragma unroll
      for (int q=0;q<16;++q)
        vp[y][q] = g_Vp[(y*64 + k*16 + q)*F + f];
    cd Vk[4][4];
    #pragma unroll
    for (int i=0;i<4;++i)
      #pragma unroll
      for (int j=0;j<4;++j){
        int q = i*4 + j;
        float2 vv = make_float2(0.0f, 0.0f);
        #pragma unroll
        for (int y=0;y<NBC;++y){ vv.x += vp[y][q].x; vv.y += vp[y][q].y; }
        Vk[i][j] = mkcd((double)vv.x,(double)vv.y);
      }
    cd M[4][4];
    #pragma unroll
    for (int i=0;i<4;++i)
      #pragma unroll
      for (int j=0;j<4;++j){
        cd s = mkcd(0.0,0.0);
        #pragma unroll
        for (int c=0;c<4;++c) s = cadd(s, cmul(W[i][c], Vk[c][j]));
        M[i][j] = s;
      }
    cd x[4];
    invcol4(M, k, x);                  // x = inv(M)[:,k]
    cd w[4];
    #pragma unroll
    for (int c=0;c<4;++c) w[c] = conj_(x[c]);
    double dre = 0.0;
    #pragma unroll
    for (int j=0;j<4;++j){
      cd tj = mkcd(0.0,0.0);
      #pragma unroll
      for (int c=0;c<4;++c) tj = cadd(tj, cmul(w[c], Vk[c][j]));
      dre += tj.re*w[j].re + tj.im*w[j].im;   // Re(tj * conj(w_j))
    }
    double inv_denom = rsqrt(dre > 0.0 ? dre : 1e-300);
    #pragma unroll
    for (int c=0;c<4;++c) W[k][c] = mkcd(w[c].re*inv_denom, w[c].im*inv_denom);
  }
  #pragma unroll
  for (int s=0;s<4;++s)
    #pragma unroll
    for (int c=0;c<4;++c) g_Wh[f*16+s*4+c] = make_float2((float)W[s][c].re, (float)W[s][c].im);

  if (do_scale){
    cd x[4];
    invcol4(W, 0, x);   // x = inv(Wh)[:,0]
    #pragma unroll
    for (int s=0;s<4;++s) g_scale[f*4+s] = make_float2((float)x[s].re, (float)x[s].im);
  }
}

// out[s,f,b] = (Wh[f] X[:,f,b])[s] * scale[f,s]; interleaved (re,im) bf16 pairs
__global__ __launch_bounds__(256) void final_kernel(
    const float* __restrict__ Xr, const float* __restrict__ Xi,
    __hip_bfloat162* __restrict__ out){
  int b = blockIdx.x*blockDim.x + threadIdx.x;
  if (b >= B) return;
  int f0 = blockIdx.y*FCH, f1 = min(f0+FCH, F);
  for (int f=f0; f<f1; ++f){
    float xr[K], xi[K];
    #pragma unroll
    for (int c=0;c<K;++c){ int idx=c*FB + f*B + b; xr[c]=Xr[idx]; xi[c]=Xi[idx]; }
    const float2* w = g_Wh + f*16;
    #pragma unroll
    for (int s=0;s<K;++s){
      float yr=0.0f, yi=0.0f;
      #pragma unroll
      for (int c=0;c<K;++c){
        float2 ww = w[s*4+c];
        yr += ww.x*xr[c] - ww.y*xi[c];
        yi += ww.x*xi[c] + ww.y*xr[c];
      }
      float2 sc = g_scale[f*4+s];
      __hip_bfloat162 o;
      o.x = __float2bfloat16(yr*sc.x - yi*sc.y);
      o.y = __float2bfloat16(yr*sc.y + yi*sc.x);
      out[s*FB + f*B + b] = o;
    }
  }
}

// ---------------- launch ----------------------------------------------------
extern "C" void kernel_launch(void* const* d_in, const int* in_sizes, int n_in,
                              void* d_out, int out_size, void* d_ws, size_t ws_size,
                              hipStream_t stream){
  // Inputs arrive alphabetized: d_in[0]="Xi", d_in[1]="Xr".
  const float* Xr = (const float*)d_in[1];
  const float* Xi = (const float*)d_in[0];
  __hip_bfloat162* out = (__hip_bfloat162*)d_out;

  init_kernel<<<33, 256, 0, stream>>>();
  dim3 gD((B + 255)/256, NFC);          // (16, 65)
  dim3 gV(F, NBC);                      // (513, 4)
  for (int it=0; it<NIT; ++it){
    demix_part_kernel<<<gD, 256, 0, stream>>>(Xr, Xi, it & 1);
    v_kernel<<<gV, 256, 0, stream>>>(Xr, Xi, it & 1);
    update_kernel<<<(F + 63)/64, 64, 0, stream>>>(it == NIT-1 ? 1 : 0, it & 1);
  }
  final_kernel<<<gD, 256, 0, stream>>>(Xr, Xi, out);
}